// Round 13
// baseline (145.224 us; speedup 1.0000x reference)
//
#include <hip/hip_runtime.h>

#define NF   16
#define C    8
#define NB   4
#define NPIX (512*512)

// plane-major sums: grid (CH, NF, NB) = 1024 blocks; each block streams one
// contiguous 64KB plane span + matching 64KB label span (R8 structure, proven).
#define CH      16
#define CPX     (NPIX / CH)          // 16384 px per chunk
#define SITERS  (CPX / (256 * 4))    // 16 iterations, 4 px per thread

// dist: DG blocks per batch (R11 structure, proven) + fused final reduce.
#define DG      256
#define DCHUNK  (NPIX / DG)          // 1024 px per block
#define NDIST   (DG * NB)            // 1024 partials

// ws float layout:
//   PSUM: [b][f][ch][8]   4*16*16*8 = 8192 floats
//   PCNT: [b][ch][8]      4*16*8    = 512
//   POUT: [g]                         1024   (atomicExch'd, atomically read)
//   CNT:  int done-counter            1      (zeroed by sums block 0)
#define WS_PSUM 0
#define WS_PCNT (NB * NF * CH * 8)
#define WS_POUT (WS_PCNT + NB * CH * 8)
#define WS_CNT  (WS_POUT + NDIST)

__global__ __launch_bounds__(256) void sums_kernel(const float* __restrict__ pred,
                                                   const int* __restrict__ tgt,
                                                   float* __restrict__ ws) {
    const int t    = threadIdx.x;
    const int lane = t & 63;
    const int wave = t >> 6;
    const int ch   = blockIdx.x;
    const int f    = blockIdx.y;
    const int b    = blockIdx.z;

    // zero the dist done-counter (stream order guarantees this precedes K2)
    if (ch == 0 && f == 0 && b == 0 && t == 0)
        ((int*)(ws + WS_CNT))[0] = 0;

    const float* pf = pred + ((size_t)b * NF + f) * NPIX + ch * CPX;
    const int*   tg = tgt  + (size_t)b * NPIX + ch * CPX;

    float acc[8];
#pragma unroll
    for (int c = 0; c < 8; ++c) acc[c] = 0.0f;
    float cnt[8];
#pragma unroll
    for (int c = 0; c < 8; ++c) cnt[c] = 0.0f;

    for (int it = 0; it < SITERS; ++it) {
        const int px = it * 1024 + t * 4;
        int4   lab = *(const int4*)(tg + px);
        float4 p   = *(const float4*)(pf + px);
        float m0[8], m1[8], m2[8], m3[8];
#pragma unroll
        for (int c = 0; c < 8; ++c) {
            m0[c] = (lab.x == c) ? 1.0f : 0.0f;
            m1[c] = (lab.y == c) ? 1.0f : 0.0f;
            m2[c] = (lab.z == c) ? 1.0f : 0.0f;
            m3[c] = (lab.w == c) ? 1.0f : 0.0f;
        }
#pragma unroll
        for (int c = 0; c < 8; ++c)
            acc[c] += m0[c] * p.x + m1[c] * p.y + m2[c] * p.z + m3[c] * p.w;
        if (f == 0) {
#pragma unroll
            for (int c = 0; c < 8; ++c)
                cnt[c] += m0[c] + m1[c] + m2[c] + m3[c];
        }
    }

    // wave butterfly, then cross-wave via LDS
#pragma unroll
    for (int off = 32; off > 0; off >>= 1)
#pragma unroll
        for (int c = 0; c < 8; ++c)
            acc[c] += __shfl_xor(acc[c], off);
    if (f == 0) {
#pragma unroll
        for (int off = 32; off > 0; off >>= 1)
#pragma unroll
            for (int c = 0; c < 8; ++c)
                cnt[c] += __shfl_xor(cnt[c], off);
    }

    __shared__ float sred[4][8];
    __shared__ float scred[4][8];
    if (lane == 0) {
#pragma unroll
        for (int c = 0; c < 8; ++c) sred[wave][c] = acc[c];
        if (f == 0)
#pragma unroll
            for (int c = 0; c < 8; ++c) scred[wave][c] = cnt[c];
    }
    __syncthreads();
    if (t < 8)
        ws[WS_PSUM + (((size_t)b * NF + f) * CH + ch) * 8 + t] =
            sred[0][t] + sred[1][t] + sred[2][t] + sred[3][t];
    if (f == 0 && t >= 8 && t < 16) {
        const int c = t - 8;
        ws[WS_PCNT + (b * CH + ch) * 8 + c] =
            scred[0][c] + scred[1][c] + scred[2][c] + scred[3][c];
    }
}

// dist with in-block means reduction (R11 prologue) + fused final:
// each block commits its partial with a device-scope atomicExch, fences,
// increments a done-counter; the last block reduces all 1024 partials with
// device-scope atomic reads (safe across non-coherent XCD L2s) -> out[0].
__global__ __launch_bounds__(256) void dist_kernel(const float* __restrict__ pred,
                                                   const int* __restrict__ tgt,
                                                   const float* __restrict__ wsr,
                                                   float* __restrict__ ws,
                                                   float* __restrict__ out) {
    __shared__ float sm_p[2][128];
    __shared__ float scnt_p[8][8];
    __shared__ float scnt[8];
    __shared__ float s_means[128];
    __shared__ float s_invs;
    __shared__ float s_red[4];
    __shared__ int   s_last;
    const int tid = threadIdx.x;
    const int b   = blockIdx.y;
    const int g   = b * DG + blockIdx.x;

    // counts: t<64 -> c=t&7, grp=t>>3 sums CH/8=2 chunks
    if (tid < 64) {
        const int c = tid & 7, grp = tid >> 3;
        float s = 0.0f;
#pragma unroll
        for (int i = 0; i < 2; ++i)
            s += wsr[WS_PCNT + (b * CH + grp * 2 + i) * 8 + c];
        scnt_p[grp][c] = s;
    }
    // sums: fc = t&127, half = t>>7 sums 8 chunks each
    {
        const int fc = tid & 127, half = tid >> 7;
        const int f = fc >> 3, c = fc & 7;
        float s = 0.0f;
#pragma unroll
        for (int i = 0; i < 8; ++i)
            s += wsr[WS_PSUM + (((size_t)b * NF + f) * CH + half * 8 + i) * 8 + c];
        sm_p[half][fc] = s;
    }
    __syncthreads();
    if (tid < 8) {
        float s = 0.0f;
#pragma unroll
        for (int grp = 0; grp < 8; ++grp) s += scnt_p[grp][tid];
        scnt[tid] = s;
    }
    __syncthreads();
    if (tid < 128)
        s_means[tid] = (sm_p[0][tid] + sm_p[1][tid]) / scnt[tid & 7];
    if (tid == 0) {
        float iv = 0.0f;
#pragma unroll
        for (int c = 0; c < 8; ++c) iv += 1.0f / scnt[c];
        s_invs = iv;
    }
    __syncthreads();

    const float* predb = pred + (size_t)b * NF * NPIX;
    const int*   tgtb  = tgt  + (size_t)b * NPIX;

    const int base = blockIdx.x * DCHUNK + tid * 4;
    int4 lab = *(const int4*)(tgtb + base);
    float s0 = 0.f, s1 = 0.f, s2 = 0.f, s3 = 0.f;
#pragma unroll
    for (int f = 0; f < NF; ++f) {
        float4 p = *(const float4*)(predb + f * NPIX + base);
        float d0 = s_means[f * C + lab.x] - p.x;
        float d1 = s_means[f * C + lab.y] - p.y;
        float d2 = s_means[f * C + lab.z] - p.z;
        float d3 = s_means[f * C + lab.w] - p.w;
        s0 += d0 * d0; s1 += d1 * d1; s2 += d2 * d2; s3 += d3 * d3;
    }
    float t0 = fminf(fmaxf(sqrtf(s0) - 0.5f, 0.0f), 100000.0f);
    float t1 = fminf(fmaxf(sqrtf(s1) - 0.5f, 0.0f), 100000.0f);
    float t2 = fminf(fmaxf(sqrtf(s2) - 0.5f, 0.0f), 100000.0f);
    float t3 = fminf(fmaxf(sqrtf(s3) - 0.5f, 0.0f), 100000.0f);
    float acc = t0 * t0 + t1 * t1 + t2 * t2 + t3 * t3;

#pragma unroll
    for (int off = 32; off > 0; off >>= 1) acc += __shfl_down(acc, off);
    const int lane = tid & 63, wave = tid >> 6;
    if (lane == 0) s_red[wave] = acc;
    __syncthreads();
    if (tid == 0) {
        float tot = (s_red[0] + s_red[1] + s_red[2] + s_red[3]) * s_invs * 0.125f;
        atomicExch(&ws[WS_POUT + g], tot);      // device-scope commit
        __threadfence();
        int old = atomicAdd((int*)(ws + WS_CNT), 1);
        s_last = (old == NDIST - 1) ? 1 : 0;
    }
    __syncthreads();

    if (s_last) {
        // last block: reduce all 1024 partials via device-scope atomic reads
        float v = 0.0f;
#pragma unroll
        for (int i = 0; i < NDIST / 256; ++i)
            v += atomicAdd(&ws[WS_POUT + i * 256 + tid], 0.0f);
#pragma unroll
        for (int off = 32; off > 0; off >>= 1) v += __shfl_xor(v, off);
        if (lane == 0) s_red[wave] = v;
        __syncthreads();
        if (tid == 0)
            out[0] = s_red[0] + s_red[1] + s_red[2] + s_red[3];
    }
}

extern "C" void kernel_launch(void* const* d_in, const int* in_sizes, int n_in,
                              void* d_out, int out_size, void* d_ws, size_t ws_size,
                              hipStream_t stream) {
    const float* pred = (const float*)d_in[0];
    const int*   tgt  = (const int*)d_in[1];
    float* out = (float*)d_out;
    float* ws  = (float*)d_ws;

    sums_kernel<<<dim3(CH, NF, NB), dim3(256), 0, stream>>>(pred, tgt, ws);
    dist_kernel<<<dim3(DG, NB), dim3(256), 0, stream>>>(pred, tgt, ws, ws, out);
}

// Round 14
// 119.315 us; speedup vs baseline: 1.2171x; 1.2171x over previous
//
#include <hip/hip_runtime.h>

#define NF   16
#define C    8
#define NB   4
#define NPIX (512*512)

// sums: 512 blocks x 1024 threads (16 waves/block -> 16 waves/CU installed in
// one dispatch wave). Plane-major: block (ch,f,b) streams one contiguous
// 128KB plane span + label span. 8 int4-iterations per thread.
#define CH      8
#define CPX     (NPIX / CH)          // 32768 px per chunk
#define SITERS  (CPX / (1024 * 4))   // 8 iterations

// dist: 256 blocks x 1024 threads, 1 block/CU, 4 px per thread straight-line.
#define DG      64
#define DCHUNK  (NPIX / DG)          // 4096 px per block

// ws float layout (plain stores only; no atomics anywhere):
//   PSUM: [b][f][ch][8]   4*16*8*8 = 4096 floats
//   PCNT: [b][ch][8]      4*8*8    = 256
//   MEAN: [b][128]  fc = f*8+c       512
//   INV:  [b]                        4
//   POUT: [b][DG]                    256
#define WS_PSUM 0
#define WS_PCNT (NB * NF * CH * 8)
#define WS_MEAN (WS_PCNT + NB * CH * 8)
#define WS_INV  (WS_MEAN + NB * 128)
#define WS_POUT (WS_INV + NB)

__global__ __launch_bounds__(1024) void sums_kernel(const float* __restrict__ pred,
                                                    const int* __restrict__ tgt,
                                                    float* __restrict__ ws) {
    const int t    = threadIdx.x;          // 0..1023
    const int lane = t & 63;
    const int wave = t >> 6;               // 0..15
    const int ch   = blockIdx.x;
    const int f    = blockIdx.y;
    const int b    = blockIdx.z;

    const float* pf = pred + ((size_t)b * NF + f) * NPIX + ch * CPX;
    const int*   tg = tgt  + (size_t)b * NPIX + ch * CPX;

    float acc[8];
#pragma unroll
    for (int c = 0; c < 8; ++c) acc[c] = 0.0f;
    float cnt[8];
#pragma unroll
    for (int c = 0; c < 8; ++c) cnt[c] = 0.0f;

#pragma unroll 2
    for (int it = 0; it < SITERS; ++it) {
        const int px = it * 4096 + t * 4;
        int4   lab = *(const int4*)(tg + px);
        float4 p   = *(const float4*)(pf + px);
        float m0[8], m1[8], m2[8], m3[8];
#pragma unroll
        for (int c = 0; c < 8; ++c) {
            m0[c] = (lab.x == c) ? 1.0f : 0.0f;
            m1[c] = (lab.y == c) ? 1.0f : 0.0f;
            m2[c] = (lab.z == c) ? 1.0f : 0.0f;
            m3[c] = (lab.w == c) ? 1.0f : 0.0f;
        }
#pragma unroll
        for (int c = 0; c < 8; ++c)
            acc[c] += m0[c] * p.x + m1[c] * p.y + m2[c] * p.z + m3[c] * p.w;
        if (f == 0) {
#pragma unroll
            for (int c = 0; c < 8; ++c)
                cnt[c] += m0[c] + m1[c] + m2[c] + m3[c];
        }
    }

    // wave butterfly, then cross-wave (16 waves) via LDS
#pragma unroll
    for (int off = 32; off > 0; off >>= 1)
#pragma unroll
        for (int c = 0; c < 8; ++c)
            acc[c] += __shfl_xor(acc[c], off);
    if (f == 0) {
#pragma unroll
        for (int off = 32; off > 0; off >>= 1)
#pragma unroll
            for (int c = 0; c < 8; ++c)
                cnt[c] += __shfl_xor(cnt[c], off);
    }

    __shared__ float sred[16][8];
    __shared__ float scred[16][8];
    if (lane == 0) {
#pragma unroll
        for (int c = 0; c < 8; ++c) sred[wave][c] = acc[c];
        if (f == 0)
#pragma unroll
            for (int c = 0; c < 8; ++c) scred[wave][c] = cnt[c];
    }
    __syncthreads();
    if (t < 8) {
        float s = 0.0f;
#pragma unroll
        for (int w = 0; w < 16; ++w) s += sred[w][t];
        ws[WS_PSUM + (((size_t)b * NF + f) * CH + ch) * 8 + t] = s;
    }
    if (f == 0 && t >= 8 && t < 16) {
        const int c = t - 8;
        float s = 0.0f;
#pragma unroll
        for (int w = 0; w < 16; ++w) s += scred[w][c];
        ws[WS_PCNT + (b * CH + ch) * 8 + c] = s;
    }
}

// One block, 512 threads: reduce 8 chunk-partials per (b,fc), means + invsum.
__global__ void means_kernel(float* __restrict__ ws) {
    __shared__ float scnt[32];
    const int t = threadIdx.x;
    if (t < 32) {
        const int b = t >> 3, c = t & 7;
        float s = 0.0f;
#pragma unroll
        for (int ch = 0; ch < CH; ++ch)
            s += ws[WS_PCNT + (b * CH + ch) * 8 + c];
        scnt[t] = s;
    }
    __syncthreads();
    const int b = t >> 7, fc = t & 127, f = fc >> 3, c = fc & 7;
    float s = 0.0f;
#pragma unroll
    for (int ch = 0; ch < CH; ++ch)
        s += ws[WS_PSUM + (((size_t)b * NF + f) * CH + ch) * 8 + c];
    ws[WS_MEAN + b * 128 + fc] = s / scnt[b * 8 + c];
    if (fc == 0) {
        float iv = 0.0f;
#pragma unroll
        for (int c8 = 0; c8 < 8; ++c8) iv += 1.0f / scnt[b * 8 + c8];
        ws[WS_INV + b] = iv;
    }
}

__global__ __launch_bounds__(1024) void dist_kernel(const float* __restrict__ pred,
                                                    const int* __restrict__ tgt,
                                                    const float* __restrict__ ws,
                                                    float* __restrict__ pout) {
    __shared__ float s_means[C * NF];
    __shared__ float s_red[16];
    const int tid = threadIdx.x;           // 0..1023
    const int b   = blockIdx.y;
    if (tid < C * NF) s_means[tid] = ws[WS_MEAN + b * 128 + tid];
    const float invs = ws[WS_INV + b];
    __syncthreads();

    const float* predb = pred + (size_t)b * NF * NPIX;
    const int*   tgtb  = tgt  + (size_t)b * NPIX;

    const int base = blockIdx.x * DCHUNK + tid * 4;
    int4 lab = *(const int4*)(tgtb + base);
    float s0 = 0.f, s1 = 0.f, s2 = 0.f, s3 = 0.f;
#pragma unroll
    for (int f = 0; f < NF; ++f) {
        float4 p = *(const float4*)(predb + f * NPIX + base);
        float d0 = s_means[f * C + lab.x] - p.x;
        float d1 = s_means[f * C + lab.y] - p.y;
        float d2 = s_means[f * C + lab.z] - p.z;
        float d3 = s_means[f * C + lab.w] - p.w;
        s0 += d0 * d0; s1 += d1 * d1; s2 += d2 * d2; s3 += d3 * d3;
    }
    float t0 = fminf(fmaxf(sqrtf(s0) - 0.5f, 0.0f), 100000.0f);
    float t1 = fminf(fmaxf(sqrtf(s1) - 0.5f, 0.0f), 100000.0f);
    float t2 = fminf(fmaxf(sqrtf(s2) - 0.5f, 0.0f), 100000.0f);
    float t3 = fminf(fmaxf(sqrtf(s3) - 0.5f, 0.0f), 100000.0f);
    float acc = t0 * t0 + t1 * t1 + t2 * t2 + t3 * t3;

#pragma unroll
    for (int off = 32; off > 0; off >>= 1) acc += __shfl_down(acc, off);
    const int lane = tid & 63, wave = tid >> 6;
    if (lane == 0) s_red[wave] = acc;
    __syncthreads();
    if (tid == 0) {
        float tot = 0.0f;
#pragma unroll
        for (int w = 0; w < 16; ++w) tot += s_red[w];
        pout[b * DG + blockIdx.x] = tot * invs * 0.125f;
    }
}

// One block, 256 threads: sum the 256 dist partials, plain store to out.
__global__ void final_kernel(const float* __restrict__ pout, float* __restrict__ out) {
    __shared__ float sr[4];
    const int t = threadIdx.x;
    float v = pout[t];
#pragma unroll
    for (int off = 32; off > 0; off >>= 1) v += __shfl_xor(v, off);
    if ((t & 63) == 0) sr[t >> 6] = v;
    __syncthreads();
    if (t == 0)
        out[0] = sr[0] + sr[1] + sr[2] + sr[3];
}

extern "C" void kernel_launch(void* const* d_in, const int* in_sizes, int n_in,
                              void* d_out, int out_size, void* d_ws, size_t ws_size,
                              hipStream_t stream) {
    const float* pred = (const float*)d_in[0];
    const int*   tgt  = (const int*)d_in[1];
    float* out = (float*)d_out;
    float* ws  = (float*)d_ws;

    sums_kernel<<<dim3(CH, NF, NB), dim3(1024), 0, stream>>>(pred, tgt, ws);
    means_kernel<<<dim3(1), dim3(512), 0, stream>>>(ws);
    dist_kernel<<<dim3(DG, NB), dim3(1024), 0, stream>>>(pred, tgt, ws, ws + WS_POUT);
    final_kernel<<<dim3(1), dim3(256), 0, stream>>>(ws + WS_POUT, out);
}